// Round 1
// 14275.652 us; speedup vs baseline: 2.3569x; 2.3569x over previous
//
#include <hip/hip_runtime.h>
#include <hip/hip_bf16.h>
#include <math.h>

// Problem constants
constexpr int B_  = 64;
constexpr int T_  = 120;
constexpr int TITLE_ = 20;
constexpr int H_  = 768;
constexpr int L_  = 12;
constexpr int NH_ = 12;
constexpr int DH_ = 64;
constexpr int FF_ = 3072;
constexpr int V_  = 21128;
constexpr int M_  = B_ * T_;      // 7680 tokens
constexpr int VC_ = 2048;         // classifier V-chunk width

typedef __attribute__((ext_vector_type(8))) _Float16 f16x8;
typedef __attribute__((ext_vector_type(4))) _Float16 f16x4;
typedef __attribute__((ext_vector_type(4))) float f32x4;

// ---------------- block reductions (any blockDim multiple of 64, <=512) ----
__device__ __forceinline__ float block_reduce_sum(float v) {
  __shared__ float red[8];
  #pragma unroll
  for (int o = 32; o > 0; o >>= 1) v += __shfl_down(v, o, 64);
  int lane = threadIdx.x & 63, w = threadIdx.x >> 6;
  __syncthreads();
  if (lane == 0) red[w] = v;
  __syncthreads();
  float total = 0.0f;
  int nw = (blockDim.x + 63) >> 6;
  for (int i = 0; i < nw; i++) total += red[i];
  return total;
}

__device__ __forceinline__ float block_reduce_max(float v) {
  __shared__ float red[8];
  #pragma unroll
  for (int o = 32; o > 0; o >>= 1) v = fmaxf(v, __shfl_down(v, o, 64));
  int lane = threadIdx.x & 63, w = threadIdx.x >> 6;
  __syncthreads();
  if (lane == 0) red[w] = v;
  __syncthreads();
  float total = -1e30f;
  int nw = (blockDim.x + 63) >> 6;
  for (int i = 0; i < nw; i++) total = fmaxf(total, red[i]);
  return total;
}

// ---------------- embedding + LN --------------------------------------------
__global__ __launch_bounds__(256) void embed_ln_kernel(
    const int* __restrict__ x, const float* __restrict__ we,
    const float* __restrict__ pe, const float* __restrict__ te,
    const float* __restrict__ g, const float* __restrict__ b,
    float* __restrict__ h) {
  int tok = blockIdx.x;
  int t = tok % T_;
  int wid = x[tok];
  int tid = threadIdx.x;
  float vals[3];
  float lsum = 0.0f;
  #pragma unroll
  for (int i = 0; i < 3; i++) {
    int c = tid + i * 256;
    float v = we[wid * H_ + c] + pe[t * H_ + c] + te[c];
    vals[i] = v; lsum += v;
  }
  float mean = block_reduce_sum(lsum) * (1.0f / H_);
  float lvar = 0.0f;
  #pragma unroll
  for (int i = 0; i < 3; i++) { float d = vals[i] - mean; lvar += d * d; }
  float var = block_reduce_sum(lvar) * (1.0f / H_);
  float rstd = rsqrtf(var + 1e-12f);
  #pragma unroll
  for (int i = 0; i < 3; i++) {
    int c = tid + i * 256;
    h[tok * H_ + c] = (vals[i] - mean) * rstd * g[c] + b[c];
  }
}

// ---------------- residual + LN (in place on h) ------------------------------
__global__ __launch_bounds__(256) void resid_ln_kernel(
    float* __restrict__ h, const float* __restrict__ delta,
    const float* __restrict__ g, const float* __restrict__ b) {
  int tok = blockIdx.x;
  int tid = threadIdx.x;
  float vals[3];
  float lsum = 0.0f;
  #pragma unroll
  for (int i = 0; i < 3; i++) {
    int c = tid + i * 256;
    float v = h[tok * H_ + c] + delta[tok * H_ + c];
    vals[i] = v; lsum += v;
  }
  float mean = block_reduce_sum(lsum) * (1.0f / H_);
  float lvar = 0.0f;
  #pragma unroll
  for (int i = 0; i < 3; i++) { float d = vals[i] - mean; lvar += d * d; }
  float var = block_reduce_sum(lvar) * (1.0f / H_);
  float rstd = rsqrtf(var + 1e-12f);
  #pragma unroll
  for (int i = 0; i < 3; i++) {
    int c = tid + i * 256;
    h[tok * H_ + c] = (vals[i] - mean) * rstd * g[c] + b[c];
  }
}

// ---------------- split-fp16 MFMA GEMM ---------------------------------------
// C[M,N] = A[M,K](f32) @ W[K,N](f32) + bias, via 3-term fp16 split:
//   A ~= Ah + Al, W ~= Wh + Wl  ->  acc += Ah*Wh + Ah*Wl + Al*Wh  (f32 MFMA acc)
// M multiple of 128, K multiple of 32, N arbitrary (guarded).
// 128x128 tile, BK=32, 4 waves in 2x2, each wave 64x64 (4x4 frags of 16x16x32).
template <int ACT>
__global__ __launch_bounds__(256, 2) void gemm_mfma(
    const float* __restrict__ A, const float* __restrict__ W,
    const float* __restrict__ bias, float* __restrict__ C,
    int M, int N, int K, int ldw) {
  constexpr int BM = 128, BN = 128, BK = 32;
  constexpr int PITCH = BK + 8;   // 40 halves (80B rows): frag b128 reads land 2-way (free)
  __shared__ _Float16 AsH[BM * PITCH];
  __shared__ _Float16 AsL[BM * PITCH];
  __shared__ _Float16 WsH[BN * PITCH];
  __shared__ _Float16 WsL[BN * PITCH];

  const int tid = threadIdx.x;
  const int lane = tid & 63;
  const int wv = tid >> 6;
  const int wm = wv >> 1, wn = wv & 1;      // 2x2 wave grid
  const int lr = lane & 15, lg = lane >> 4; // frag row/col and k-group
  const int m0 = blockIdx.y * BM, n0 = blockIdx.x * BN;

  // A staging: thread -> (row ar+p*32, k-cols ac..ac+3), float4 coalesced
  const int ar = tid >> 3;
  const int ac = (tid & 7) * 4;
  // W staging (transposed store): thread -> (k rows wkr..wkr+3, n col wnl+p*32)
  const int wkr = (tid >> 5) * 4;
  const int wnl = tid & 31;

  f32x4 acc[4][4] = {};
  float4 aReg[4];
  float  wReg[4][4];

  auto load_tile = [&](int k0) {
    #pragma unroll
    for (int p = 0; p < 4; p++)
      aReg[p] = *reinterpret_cast<const float4*>(
          &A[(size_t)(m0 + ar + p * 32) * K + k0 + ac]);
    #pragma unroll
    for (int p = 0; p < 4; p++) {
      int n = n0 + wnl + p * 32;
      #pragma unroll
      for (int i = 0; i < 4; i++)
        wReg[p][i] = (n < N) ? W[(size_t)(k0 + wkr + i) * ldw + n] : 0.0f;
    }
  };

  auto write_tile = [&]() {
    #pragma unroll
    for (int p = 0; p < 4; p++) {
      float vx[4] = {aReg[p].x, aReg[p].y, aReg[p].z, aReg[p].w};
      f16x4 h, l;
      #pragma unroll
      for (int i = 0; i < 4; i++) {
        _Float16 hv = (_Float16)vx[i];
        h[i] = hv;
        l[i] = (_Float16)(vx[i] - (float)hv);
      }
      int row = ar + p * 32;
      *reinterpret_cast<f16x4*>(&AsH[row * PITCH + ac]) = h;
      *reinterpret_cast<f16x4*>(&AsL[row * PITCH + ac]) = l;
    }
    #pragma unroll
    for (int p = 0; p < 4; p++) {
      f16x4 h, l;
      #pragma unroll
      for (int i = 0; i < 4; i++) {
        _Float16 hv = (_Float16)wReg[p][i];
        h[i] = hv;
        l[i] = (_Float16)(wReg[p][i] - (float)hv);
      }
      int row = wnl + p * 32;
      *reinterpret_cast<f16x4*>(&WsH[row * PITCH + wkr]) = h;
      *reinterpret_cast<f16x4*>(&WsL[row * PITCH + wkr]) = l;
    }
  };

  load_tile(0);
  const int nsteps = K / BK;
  for (int t = 0; t < nsteps; t++) {
    write_tile();
    if (t + 1 < nsteps) load_tile((t + 1) * BK);  // issue-early: hides HBM under MFMA
    __syncthreads();
    f16x8 ah[4], al[4], bh[4], bl[4];
    #pragma unroll
    for (int i = 0; i < 4; i++) {
      int arow = wm * 64 + i * 16 + lr;
      ah[i] = *reinterpret_cast<const f16x8*>(&AsH[arow * PITCH + lg * 8]);
      al[i] = *reinterpret_cast<const f16x8*>(&AsL[arow * PITCH + lg * 8]);
      int brow = wn * 64 + i * 16 + lr;
      bh[i] = *reinterpret_cast<const f16x8*>(&WsH[brow * PITCH + lg * 8]);
      bl[i] = *reinterpret_cast<const f16x8*>(&WsL[brow * PITCH + lg * 8]);
    }
    #pragma unroll
    for (int i = 0; i < 4; i++)
      #pragma unroll
      for (int j = 0; j < 4; j++) {
        acc[i][j] = __builtin_amdgcn_mfma_f32_16x16x32_f16(ah[i], bh[j], acc[i][j], 0, 0, 0);
        acc[i][j] = __builtin_amdgcn_mfma_f32_16x16x32_f16(ah[i], bl[j], acc[i][j], 0, 0, 0);
        acc[i][j] = __builtin_amdgcn_mfma_f32_16x16x32_f16(al[i], bh[j], acc[i][j], 0, 0, 0);
      }
    __syncthreads();
  }

  // epilogue: C/D layout col=lane&15, row=(lane>>4)*4+reg (m89-verified)
  #pragma unroll
  for (int i = 0; i < 4; i++) {
    #pragma unroll
    for (int j = 0; j < 4; j++) {
      int ncol = n0 + wn * 64 + j * 16 + lr;
      if (ncol < N) {
        float bv = bias[ncol];
        #pragma unroll
        for (int r = 0; r < 4; r++) {
          int m = m0 + wm * 64 + i * 16 + lg * 4 + r;
          float v = acc[i][j][r] + bv;
          if (ACT == 1) v = 0.5f * v * (1.0f + erff(v * 0.70710678118654752f));
          C[(size_t)m * N + ncol] = v;
        }
      }
    }
  }
}

// ---------------- fused attention: one block per (b, head, q-row) ------------
__global__ __launch_bounds__(128) void attn_fused_kernel(
    const float* __restrict__ qb, const float* __restrict__ kb,
    const float* __restrict__ vb, float* __restrict__ ctx) {
  int bid = blockIdx.x;                // b*NH*T + hh*T + qt
  int qt = bid % T_;
  int rem = bid / T_;
  int hh = rem % NH_;
  int b = rem / NH_;
  int tid = threadIdx.x;
  __shared__ float qrow[DH_];
  __shared__ float sc[T_];

  const float* qptr = qb + ((size_t)(b * T_ + qt) * H_ + hh * DH_);
  if (tid < DH_) qrow[tid] = qptr[tid];
  __syncthreads();

  float sval = -1e30f;
  if (tid < T_) {
    const float* kptr = kb + ((size_t)(b * T_ + tid) * H_ + hh * DH_);
    float s = 0.0f;
    #pragma unroll 8
    for (int d = 0; d < DH_; d++) s += qrow[d] * kptr[d];
    s *= 0.125f;  // 1/sqrt(64)
    bool allowed = (tid < TITLE_) || (qt >= TITLE_ && tid <= qt);
    if (!allowed) s -= 10000.0f;
    sc[tid] = s;
    sval = s;
  }
  float mx = block_reduce_max(sval);
  float ex = 0.0f;
  if (tid < T_) { ex = expf(sc[tid] - mx); sc[tid] = ex; }
  float denom = block_reduce_sum(ex);
  float inv = 1.0f / denom;
  if (tid < DH_) {
    float acc = 0.0f;
    const float* vcol = vb + ((size_t)b * T_ * H_ + hh * DH_ + tid);
    for (int t = 0; t < T_; t++) acc += sc[t] * vcol[(size_t)t * H_];
    ctx[(size_t)(b * T_ + qt) * H_ + hh * DH_ + tid] = acc * inv;
  }
}

// ---------------- online-softmax loss over V chunks ---------------------------
__global__ void loss_init_kernel(float* marr, float* sarr, float* ylg) {
  int i = blockIdx.x * 256 + threadIdx.x;
  if (i < M_) { marr[i] = -1e30f; sarr[i] = 0.0f; ylg[i] = 0.0f; }
}

__global__ __launch_bounds__(256) void loss_update_kernel(
    const float* __restrict__ logits, const int* __restrict__ y,
    float* __restrict__ marr, float* __restrict__ sarr, float* __restrict__ ylg,
    int c0, int vc) {
  int tok = blockIdx.x;
  int tid = threadIdx.x;
  const float* row = logits + (size_t)tok * vc;
  float lmax = -1e30f;
  for (int i = tid; i < vc; i += 256) lmax = fmaxf(lmax, row[i]);
  float cmax = block_reduce_max(lmax);
  float mold = marr[tok];
  float sold = sarr[tok];
  float mnew = fmaxf(mold, cmax);
  float lsum = 0.0f;
  for (int i = tid; i < vc; i += 256) lsum += expf(row[i] - mnew);
  float csum = block_reduce_sum(lsum);
  if (tid == 0) {
    marr[tok] = mnew;
    sarr[tok] = sold * expf(mold - mnew) + csum;
    int yt = y[tok];
    if (yt >= c0 && yt < c0 + vc) ylg[tok] = row[yt - c0];
  }
}

__global__ __launch_bounds__(256) void loss_final_kernel(
    const float* __restrict__ marr, const float* __restrict__ sarr,
    const float* __restrict__ ylg, float* __restrict__ out) {
  int tid = threadIdx.x;
  float lsum = 0.0f;
  for (int i = tid; i < M_; i += 256)
    lsum += (marr[i] + logf(sarr[i])) - ylg[i];
  float total = block_reduce_sum(lsum);
  if (tid == 0) out[0] = total / (float)M_;
}

// ---------------- host orchestration -----------------------------------------
extern "C" void kernel_launch(void* const* d_in, const int* in_sizes, int n_in,
                              void* d_out, int out_size, void* d_ws, size_t ws_size,
                              hipStream_t stream) {
  const int*   x        = (const int*)d_in[0];
  const int*   y        = (const int*)d_in[1];
  const float* word_emb = (const float*)d_in[2];
  const float* pos_emb  = (const float*)d_in[3];
  const float* type_emb = (const float*)d_in[4];
  const float* emb_ln_g = (const float*)d_in[5];
  const float* emb_ln_b = (const float*)d_in[6];
  const float* Wq = (const float*)d_in[7];
  const float* Wk = (const float*)d_in[8];
  const float* Wv = (const float*)d_in[9];
  const float* Wo = (const float*)d_in[10];
  const float* W1 = (const float*)d_in[11];
  const float* W2 = (const float*)d_in[12];
  const float* bq = (const float*)d_in[13];
  const float* bk = (const float*)d_in[14];
  const float* bv = (const float*)d_in[15];
  const float* bo = (const float*)d_in[16];
  const float* b1 = (const float*)d_in[17];
  const float* b2 = (const float*)d_in[18];
  const float* ln1_g = (const float*)d_in[19];
  const float* ln1_b = (const float*)d_in[20];
  const float* ln2_g = (const float*)d_in[21];
  const float* ln2_b = (const float*)d_in[22];
  const float* Wc = (const float*)d_in[23];
  const float* bc = (const float*)d_in[24];

  float* ws   = (float*)d_ws;
  float* h    = ws;
  float* tmp  = ws + 5898240;
  float* buf2 = ws + 29491200;
  float* marr = ws + 35389440;
  float* sarr = marr + M_;
  float* ylg  = sarr + M_;

  float* q = tmp;
  float* k = tmp + (size_t)M_ * H_;
  float* v = tmp + (size_t)2 * M_ * H_;

  dim3 blk256(256);
  dim3 gH(H_ / 128, M_ / 128);     // 6 x 60
  dim3 gFF(FF_ / 128, M_ / 128);   // 24 x 60

  embed_ln_kernel<<<M_, blk256, 0, stream>>>(x, word_emb, pos_emb, type_emb,
                                             emb_ln_g, emb_ln_b, h);

  for (int l = 0; l < L_; l++) {
    const float* Wq_l = Wq + (size_t)l * H_ * H_;
    const float* Wk_l = Wk + (size_t)l * H_ * H_;
    const float* Wv_l = Wv + (size_t)l * H_ * H_;
    const float* Wo_l = Wo + (size_t)l * H_ * H_;
    const float* W1_l = W1 + (size_t)l * H_ * FF_;
    const float* W2_l = W2 + (size_t)l * FF_ * H_;

    gemm_mfma<0><<<gH, blk256, 0, stream>>>(h, Wq_l, bq + l * H_, q, M_, H_, H_, H_);
    gemm_mfma<0><<<gH, blk256, 0, stream>>>(h, Wk_l, bk + l * H_, k, M_, H_, H_, H_);
    gemm_mfma<0><<<gH, blk256, 0, stream>>>(h, Wv_l, bv + l * H_, v, M_, H_, H_, H_);

    attn_fused_kernel<<<B_ * NH_ * T_, 128, 0, stream>>>(q, k, v, buf2);

    gemm_mfma<0><<<gH, blk256, 0, stream>>>(buf2, Wo_l, bo + l * H_, tmp, M_, H_, H_, H_);
    resid_ln_kernel<<<M_, blk256, 0, stream>>>(h, tmp, ln1_g + l * H_, ln1_b + l * H_);

    gemm_mfma<1><<<gFF, blk256, 0, stream>>>(h, W1_l, b1 + l * FF_, tmp, M_, FF_, H_, FF_);
    gemm_mfma<0><<<gH, blk256, 0, stream>>>(tmp, W2_l, b2 + l * H_, buf2, M_, H_, FF_, H_);
    resid_ln_kernel<<<M_, blk256, 0, stream>>>(h, buf2, ln2_g + l * H_, ln2_b + l * H_);
  }

  // classifier + online-softmax NLL, chunked over V
  loss_init_kernel<<<(M_ + 255) / 256, blk256, 0, stream>>>(marr, sarr, ylg);
  for (int c0 = 0; c0 < V_; c0 += VC_) {
    int vc = (V_ - c0) < VC_ ? (V_ - c0) : VC_;
    dim3 gC((vc + 127) / 128, M_ / 128);
    gemm_mfma<0><<<gC, blk256, 0, stream>>>(h, Wc + c0, bc + c0, tmp, M_, vc, H_, V_);
    loss_update_kernel<<<M_, blk256, 0, stream>>>(tmp, y, marr, sarr, ylg, c0, vc);
  }
  loss_final_kernel<<<1, blk256, 0, stream>>>(marr, sarr, ylg, (float*)d_out);
}

// Round 2
// 8981.205 us; speedup vs baseline: 3.7462x; 1.5895x over previous
//
#include <hip/hip_runtime.h>
#include <hip/hip_bf16.h>
#include <math.h>

// Problem constants
constexpr int B_  = 64;
constexpr int T_  = 120;
constexpr int TITLE_ = 20;
constexpr int H_  = 768;
constexpr int L_  = 12;
constexpr int NH_ = 12;
constexpr int DH_ = 64;
constexpr int FF_ = 3072;
constexpr int V_  = 21128;
constexpr int M_  = B_ * T_;      // 7680 tokens
constexpr int VC_ = 2048;         // classifier V-chunk width

typedef __attribute__((ext_vector_type(8))) _Float16 f16x8;
typedef __attribute__((ext_vector_type(4))) _Float16 f16x4;
typedef __attribute__((ext_vector_type(4))) float f32x4;

// ---------------- block reductions (any blockDim multiple of 64, <=512) ----
__device__ __forceinline__ float block_reduce_sum(float v) {
  __shared__ float red[8];
  #pragma unroll
  for (int o = 32; o > 0; o >>= 1) v += __shfl_down(v, o, 64);
  int lane = threadIdx.x & 63, w = threadIdx.x >> 6;
  __syncthreads();
  if (lane == 0) red[w] = v;
  __syncthreads();
  float total = 0.0f;
  int nw = (blockDim.x + 63) >> 6;
  for (int i = 0; i < nw; i++) total += red[i];
  return total;
}

__device__ __forceinline__ float block_reduce_max(float v) {
  __shared__ float red[8];
  #pragma unroll
  for (int o = 32; o > 0; o >>= 1) v = fmaxf(v, __shfl_down(v, o, 64));
  int lane = threadIdx.x & 63, w = threadIdx.x >> 6;
  __syncthreads();
  if (lane == 0) red[w] = v;
  __syncthreads();
  float total = -1e30f;
  int nw = (blockDim.x + 63) >> 6;
  for (int i = 0; i < nw; i++) total = fmaxf(total, red[i]);
  return total;
}

// ---------------- embedding + LN --------------------------------------------
__global__ __launch_bounds__(256) void embed_ln_kernel(
    const int* __restrict__ x, const float* __restrict__ we,
    const float* __restrict__ pe, const float* __restrict__ te,
    const float* __restrict__ g, const float* __restrict__ b,
    float* __restrict__ h) {
  int tok = blockIdx.x;
  int t = tok % T_;
  int wid = x[tok];
  int tid = threadIdx.x;
  float vals[3];
  float lsum = 0.0f;
  #pragma unroll
  for (int i = 0; i < 3; i++) {
    int c = tid + i * 256;
    float v = we[wid * H_ + c] + pe[t * H_ + c] + te[c];
    vals[i] = v; lsum += v;
  }
  float mean = block_reduce_sum(lsum) * (1.0f / H_);
  float lvar = 0.0f;
  #pragma unroll
  for (int i = 0; i < 3; i++) { float d = vals[i] - mean; lvar += d * d; }
  float var = block_reduce_sum(lvar) * (1.0f / H_);
  float rstd = rsqrtf(var + 1e-12f);
  #pragma unroll
  for (int i = 0; i < 3; i++) {
    int c = tid + i * 256;
    h[tok * H_ + c] = (vals[i] - mean) * rstd * g[c] + b[c];
  }
}

// ---------------- residual + LN (in place on h) ------------------------------
__global__ __launch_bounds__(256) void resid_ln_kernel(
    float* __restrict__ h, const float* __restrict__ delta,
    const float* __restrict__ g, const float* __restrict__ b) {
  int tok = blockIdx.x;
  int tid = threadIdx.x;
  float vals[3];
  float lsum = 0.0f;
  #pragma unroll
  for (int i = 0; i < 3; i++) {
    int c = tid + i * 256;
    float v = h[tok * H_ + c] + delta[tok * H_ + c];
    vals[i] = v; lsum += v;
  }
  float mean = block_reduce_sum(lsum) * (1.0f / H_);
  float lvar = 0.0f;
  #pragma unroll
  for (int i = 0; i < 3; i++) { float d = vals[i] - mean; lvar += d * d; }
  float var = block_reduce_sum(lvar) * (1.0f / H_);
  float rstd = rsqrtf(var + 1e-12f);
  #pragma unroll
  for (int i = 0; i < 3; i++) {
    int c = tid + i * 256;
    h[tok * H_ + c] = (vals[i] - mean) * rstd * g[c] + b[c];
  }
}

// ---------------- split-fp16 MFMA GEMM ---------------------------------------
// C[M,N] = A[M,K](f32) @ W[K,N](f32) + bias, via 3-term fp16 split.
template <int ACT>
__global__ __launch_bounds__(256, 2) void gemm_mfma(
    const float* __restrict__ A, const float* __restrict__ W,
    const float* __restrict__ bias, float* __restrict__ C,
    int M, int N, int K, int ldw) {
  constexpr int BM = 128, BN = 128, BK = 32;
  constexpr int PITCH = BK + 8;
  __shared__ _Float16 AsH[BM * PITCH];
  __shared__ _Float16 AsL[BM * PITCH];
  __shared__ _Float16 WsH[BN * PITCH];
  __shared__ _Float16 WsL[BN * PITCH];

  const int tid = threadIdx.x;
  const int lane = tid & 63;
  const int wv = tid >> 6;
  const int wm = wv >> 1, wn = wv & 1;
  const int lr = lane & 15, lg = lane >> 4;
  const int m0 = blockIdx.y * BM, n0 = blockIdx.x * BN;

  const int ar = tid >> 3;
  const int ac = (tid & 7) * 4;
  const int wkr = (tid >> 5) * 4;
  const int wnl = tid & 31;

  f32x4 acc[4][4] = {};
  float4 aReg[4];
  float  wReg[4][4];

  auto load_tile = [&](int k0) {
    #pragma unroll
    for (int p = 0; p < 4; p++)
      aReg[p] = *reinterpret_cast<const float4*>(
          &A[(size_t)(m0 + ar + p * 32) * K + k0 + ac]);
    #pragma unroll
    for (int p = 0; p < 4; p++) {
      int n = n0 + wnl + p * 32;
      #pragma unroll
      for (int i = 0; i < 4; i++)
        wReg[p][i] = (n < N) ? W[(size_t)(k0 + wkr + i) * ldw + n] : 0.0f;
    }
  };

  auto write_tile = [&]() {
    #pragma unroll
    for (int p = 0; p < 4; p++) {
      float vx[4] = {aReg[p].x, aReg[p].y, aReg[p].z, aReg[p].w};
      f16x4 h, l;
      #pragma unroll
      for (int i = 0; i < 4; i++) {
        _Float16 hv = (_Float16)vx[i];
        h[i] = hv;
        l[i] = (_Float16)(vx[i] - (float)hv);
      }
      int row = ar + p * 32;
      *reinterpret_cast<f16x4*>(&AsH[row * PITCH + ac]) = h;
      *reinterpret_cast<f16x4*>(&AsL[row * PITCH + ac]) = l;
    }
    #pragma unroll
    for (int p = 0; p < 4; p++) {
      f16x4 h, l;
      #pragma unroll
      for (int i = 0; i < 4; i++) {
        _Float16 hv = (_Float16)wReg[p][i];
        h[i] = hv;
        l[i] = (_Float16)(wReg[p][i] - (float)hv);
      }
      int row = wnl + p * 32;
      *reinterpret_cast<f16x4*>(&WsH[row * PITCH + wkr]) = h;
      *reinterpret_cast<f16x4*>(&WsL[row * PITCH + wkr]) = l;
    }
  };

  load_tile(0);
  const int nsteps = K / BK;
  for (int t = 0; t < nsteps; t++) {
    write_tile();
    if (t + 1 < nsteps) load_tile((t + 1) * BK);
    __syncthreads();
    f16x8 ah[4], al[4], bh[4], bl[4];
    #pragma unroll
    for (int i = 0; i < 4; i++) {
      int arow = wm * 64 + i * 16 + lr;
      ah[i] = *reinterpret_cast<const f16x8*>(&AsH[arow * PITCH + lg * 8]);
      al[i] = *reinterpret_cast<const f16x8*>(&AsL[arow * PITCH + lg * 8]);
      int brow = wn * 64 + i * 16 + lr;
      bh[i] = *reinterpret_cast<const f16x8*>(&WsH[brow * PITCH + lg * 8]);
      bl[i] = *reinterpret_cast<const f16x8*>(&WsL[brow * PITCH + lg * 8]);
    }
    #pragma unroll
    for (int i = 0; i < 4; i++)
      #pragma unroll
      for (int j = 0; j < 4; j++) {
        acc[i][j] = __builtin_amdgcn_mfma_f32_16x16x32_f16(ah[i], bh[j], acc[i][j], 0, 0, 0);
        acc[i][j] = __builtin_amdgcn_mfma_f32_16x16x32_f16(ah[i], bl[j], acc[i][j], 0, 0, 0);
        acc[i][j] = __builtin_amdgcn_mfma_f32_16x16x32_f16(al[i], bh[j], acc[i][j], 0, 0, 0);
      }
    __syncthreads();
  }

  #pragma unroll
  for (int i = 0; i < 4; i++) {
    #pragma unroll
    for (int j = 0; j < 4; j++) {
      int ncol = n0 + wn * 64 + j * 16 + lr;
      if (ncol < N) {
        float bv = bias[ncol];
        #pragma unroll
        for (int r = 0; r < 4; r++) {
          int m = m0 + wm * 64 + i * 16 + lg * 4 + r;
          float v = acc[i][j][r] + bv;
          if (ACT == 1) v = 0.5f * v * (1.0f + erff(v * 0.70710678118654752f));
          C[(size_t)m * N + ncol] = v;
        }
      }
    }
  }
}

// ---------------- MFMA attention: one block per (b, head) --------------------
// S = Q K^T (split-f16, 3-term), in-register masked softmax, ctx = P V
// (split-f16). 120 padded to 128 rows/cols; 8 waves, each owns 16 q-rows.
__global__ __launch_bounds__(512) void attn_mfma_kernel(
    const float* __restrict__ qb, const float* __restrict__ kb,
    const float* __restrict__ vb, float* __restrict__ ctx) {
  constexpr int KP = 72;    // K pitch (halves)
  constexpr int VP = 136;   // V^T pitch (halves)
  constexpr int PP = 136;   // P pitch (halves)
  __shared__ alignas(16) _Float16 Kh[128 * KP];
  __shared__ alignas(16) _Float16 Kl[128 * KP];
  __shared__ alignas(16) _Float16 Vth[64 * VP];
  __shared__ alignas(16) _Float16 Vtl[64 * VP];
  __shared__ alignas(16) _Float16 Ph[128 * PP];
  __shared__ alignas(16) _Float16 Pl[128 * PP];

  const int hh = blockIdx.x % NH_;
  const int b  = blockIdx.x / NH_;
  const int bt0 = b * T_;
  const int tid = threadIdx.x;
  const int lane = tid & 63;
  const int wv = tid >> 6;           // wave id 0..7
  const int lr = lane & 15, lg = lane >> 4;
  const int r0 = wv * 16;            // this wave's q-row base

  // ---- stage K (row-major) and V (transposed), both as f16 hi/lo ----------
  {
    const int sc0 = (tid & 15) * 4;          // dim-group 0..60
    #pragma unroll
    for (int pass = 0; pass < 4; pass++) {
      int t = pass * 32 + (tid >> 4);        // 0..127
      float4 kv = make_float4(0.f, 0.f, 0.f, 0.f);
      float4 vv = make_float4(0.f, 0.f, 0.f, 0.f);
      if (t < T_) {
        kv = *reinterpret_cast<const float4*>(&kb[(size_t)(bt0 + t) * H_ + hh * DH_ + sc0]);
        vv = *reinterpret_cast<const float4*>(&vb[(size_t)(bt0 + t) * H_ + hh * DH_ + sc0]);
      }
      float ka[4] = {kv.x, kv.y, kv.z, kv.w};
      f16x4 khv, klv;
      #pragma unroll
      for (int i = 0; i < 4; i++) {
        _Float16 hv = (_Float16)ka[i];
        khv[i] = hv;
        klv[i] = (_Float16)(ka[i] - (float)hv);
      }
      *reinterpret_cast<f16x4*>(&Kh[t * KP + sc0]) = khv;
      *reinterpret_cast<f16x4*>(&Kl[t * KP + sc0]) = klv;
      float va[4] = {vv.x, vv.y, vv.z, vv.w};
      #pragma unroll
      for (int i = 0; i < 4; i++) {
        _Float16 hv = (_Float16)va[i];
        Vth[(sc0 + i) * VP + t] = hv;
        Vtl[(sc0 + i) * VP + t] = (_Float16)(va[i] - (float)hv);
      }
    }
  }
  __syncthreads();

  // ---- phase A: S = Q K^T --------------------------------------------------
  // Q fragments straight from global (wave-private rows; pad rows read
  // in-workspace garbage, quarantined below).
  f16x8 aqh[2], aql[2];
  #pragma unroll
  for (int ks = 0; ks < 2; ks++) {
    const float* qp = qb + (size_t)(bt0 + r0 + lr) * H_ + hh * DH_ + ks * 32 + lg * 8;
    float4 x0 = *reinterpret_cast<const float4*>(qp);
    float4 x1 = *reinterpret_cast<const float4*>(qp + 4);
    float xs[8] = {x0.x, x0.y, x0.z, x0.w, x1.x, x1.y, x1.z, x1.w};
    #pragma unroll
    for (int e = 0; e < 8; e++) {
      _Float16 hv = (_Float16)xs[e];
      aqh[ks][e] = hv;
      aql[ks][e] = (_Float16)(xs[e] - (float)hv);
    }
  }

  f32x4 accS[8] = {};
  #pragma unroll
  for (int j = 0; j < 8; j++) {
    #pragma unroll
    for (int ks = 0; ks < 2; ks++) {
      f16x8 kh = *reinterpret_cast<const f16x8*>(&Kh[(j * 16 + lr) * KP + ks * 32 + lg * 8]);
      f16x8 kl = *reinterpret_cast<const f16x8*>(&Kl[(j * 16 + lr) * KP + ks * 32 + lg * 8]);
      accS[j] = __builtin_amdgcn_mfma_f32_16x16x32_f16(aqh[ks], kh, accS[j], 0, 0, 0);
      accS[j] = __builtin_amdgcn_mfma_f32_16x16x32_f16(aqh[ks], kl, accS[j], 0, 0, 0);
      accS[j] = __builtin_amdgcn_mfma_f32_16x16x32_f16(aql[ks], kh, accS[j], 0, 0, 0);
    }
  }

  // ---- masked softmax in registers; write unnormalized P (f16 hi/lo) ------
  float invs[4];
  #pragma unroll
  for (int rr = 0; rr < 4; rr++) {
    int row = r0 + lg * 4 + rr;
    float m = -1e30f;
    float sv[8];
    #pragma unroll
    for (int j = 0; j < 8; j++) {
      int col = j * 16 + lr;
      float s = accS[j][rr] * 0.125f;
      bool allowed = (col < TITLE_) || (row >= TITLE_ && col <= row && col < T_);
      s = allowed ? s : -1e30f;   // SET, not subtract: quarantines pad garbage
      sv[j] = s;
      m = fmaxf(m, s);
    }
    #pragma unroll
    for (int o = 8; o >= 1; o >>= 1) m = fmaxf(m, __shfl_xor(m, o, 64));
    float sum = 0.0f;
    #pragma unroll
    for (int j = 0; j < 8; j++) {
      float p = expf(sv[j] - m);
      sum += p;
      int col = j * 16 + lr;
      _Float16 ph = (_Float16)p;
      Ph[row * PP + col] = ph;
      Pl[row * PP + col] = (_Float16)(p - (float)ph);
    }
    #pragma unroll
    for (int o = 8; o >= 1; o >>= 1) sum += __shfl_xor(sum, o, 64);
    invs[rr] = 1.0f / sum;
  }
  __syncthreads();

  // ---- phase B: ctx = P V --------------------------------------------------
  f32x4 accB[4] = {};
  #pragma unroll
  for (int ks = 0; ks < 4; ks++) {
    int t0 = ks * 32 + lg * 8;
    f16x8 pah = *reinterpret_cast<const f16x8*>(&Ph[(r0 + lr) * PP + t0]);
    f16x8 pal = *reinterpret_cast<const f16x8*>(&Pl[(r0 + lr) * PP + t0]);
    #pragma unroll
    for (int tn = 0; tn < 4; tn++) {
      f16x8 vh = *reinterpret_cast<const f16x8*>(&Vth[(tn * 16 + lr) * VP + t0]);
      f16x8 vl = *reinterpret_cast<const f16x8*>(&Vtl[(tn * 16 + lr) * VP + t0]);
      accB[tn] = __builtin_amdgcn_mfma_f32_16x16x32_f16(pah, vh, accB[tn], 0, 0, 0);
      accB[tn] = __builtin_amdgcn_mfma_f32_16x16x32_f16(pah, vl, accB[tn], 0, 0, 0);
      accB[tn] = __builtin_amdgcn_mfma_f32_16x16x32_f16(pal, vh, accB[tn], 0, 0, 0);
    }
  }

  // ---- epilogue: scale by 1/rowsum, guarded coalesced write ---------------
  #pragma unroll
  for (int tn = 0; tn < 4; tn++) {
    int n = tn * 16 + lr;
    #pragma unroll
    for (int rr = 0; rr < 4; rr++) {
      int row = r0 + lg * 4 + rr;
      if (row < T_)
        ctx[(size_t)(bt0 + row) * H_ + hh * DH_ + n] = accB[tn][rr] * invs[rr];
    }
  }
}

// ---------------- online-softmax loss over V chunks ---------------------------
__global__ void loss_init_kernel(float* marr, float* sarr, float* ylg) {
  int i = blockIdx.x * 256 + threadIdx.x;
  if (i < M_) { marr[i] = -1e30f; sarr[i] = 0.0f; ylg[i] = 0.0f; }
}

__global__ __launch_bounds__(256) void loss_update_kernel(
    const float* __restrict__ logits, const int* __restrict__ y,
    float* __restrict__ marr, float* __restrict__ sarr, float* __restrict__ ylg,
    int c0, int vc) {
  int tok = blockIdx.x;
  int tid = threadIdx.x;
  const float* row = logits + (size_t)tok * vc;
  float lmax = -1e30f;
  for (int i = tid; i < vc; i += 256) lmax = fmaxf(lmax, row[i]);
  float cmax = block_reduce_max(lmax);
  float mold = marr[tok];
  float sold = sarr[tok];
  float mnew = fmaxf(mold, cmax);
  float lsum = 0.0f;
  for (int i = tid; i < vc; i += 256) lsum += expf(row[i] - mnew);
  float csum = block_reduce_sum(lsum);
  if (tid == 0) {
    marr[tok] = mnew;
    sarr[tok] = sold * expf(mold - mnew) + csum;
    int yt = y[tok];
    if (yt >= c0 && yt < c0 + vc) ylg[tok] = row[yt - c0];
  }
}

__global__ __launch_bounds__(256) void loss_final_kernel(
    const float* __restrict__ marr, const float* __restrict__ sarr,
    const float* __restrict__ ylg, float* __restrict__ out) {
  int tid = threadIdx.x;
  float lsum = 0.0f;
  for (int i = tid; i < M_; i += 256)
    lsum += (marr[i] + logf(sarr[i])) - ylg[i];
  float total = block_reduce_sum(lsum);
  if (tid == 0) out[0] = total / (float)M_;
}

// ---------------- host orchestration -----------------------------------------
extern "C" void kernel_launch(void* const* d_in, const int* in_sizes, int n_in,
                              void* d_out, int out_size, void* d_ws, size_t ws_size,
                              hipStream_t stream) {
  const int*   x        = (const int*)d_in[0];
  const int*   y        = (const int*)d_in[1];
  const float* word_emb = (const float*)d_in[2];
  const float* pos_emb  = (const float*)d_in[3];
  const float* type_emb = (const float*)d_in[4];
  const float* emb_ln_g = (const float*)d_in[5];
  const float* emb_ln_b = (const float*)d_in[6];
  const float* Wq = (const float*)d_in[7];
  const float* Wk = (const float*)d_in[8];
  const float* Wv = (const float*)d_in[9];
  const float* Wo = (const float*)d_in[10];
  const float* W1 = (const float*)d_in[11];
  const float* W2 = (const float*)d_in[12];
  const float* bq = (const float*)d_in[13];
  const float* bk = (const float*)d_in[14];
  const float* bv = (const float*)d_in[15];
  const float* bo = (const float*)d_in[16];
  const float* b1 = (const float*)d_in[17];
  const float* b2 = (const float*)d_in[18];
  const float* ln1_g = (const float*)d_in[19];
  const float* ln1_b = (const float*)d_in[20];
  const float* ln2_g = (const float*)d_in[21];
  const float* ln2_b = (const float*)d_in[22];
  const float* Wc = (const float*)d_in[23];
  const float* bc = (const float*)d_in[24];

  float* ws   = (float*)d_ws;
  float* h    = ws;
  float* tmp  = ws + 5898240;
  float* buf2 = ws + 29491200;
  float* marr = ws + 35389440;
  float* sarr = marr + M_;
  float* ylg  = sarr + M_;

  float* q = tmp;
  float* k = tmp + (size_t)M_ * H_;
  float* v = tmp + (size_t)2 * M_ * H_;

  dim3 blk256(256);
  dim3 gH(H_ / 128, M_ / 128);     // 6 x 60
  dim3 gFF(FF_ / 128, M_ / 128);   // 24 x 60

  embed_ln_kernel<<<M_, blk256, 0, stream>>>(x, word_emb, pos_emb, type_emb,
                                             emb_ln_g, emb_ln_b, h);

  for (int l = 0; l < L_; l++) {
    const float* Wq_l = Wq + (size_t)l * H_ * H_;
    const float* Wk_l = Wk + (size_t)l * H_ * H_;
    const float* Wv_l = Wv + (size_t)l * H_ * H_;
    const float* Wo_l = Wo + (size_t)l * H_ * H_;
    const float* W1_l = W1 + (size_t)l * H_ * FF_;
    const float* W2_l = W2 + (size_t)l * FF_ * H_;

    gemm_mfma<0><<<gH, blk256, 0, stream>>>(h, Wq_l, bq + l * H_, q, M_, H_, H_, H_);
    gemm_mfma<0><<<gH, blk256, 0, stream>>>(h, Wk_l, bk + l * H_, k, M_, H_, H_, H_);
    gemm_mfma<0><<<gH, blk256, 0, stream>>>(h, Wv_l, bv + l * H_, v, M_, H_, H_, H_);

    attn_mfma_kernel<<<B_ * NH_, 512, 0, stream>>>(q, k, v, buf2);

    gemm_mfma<0><<<gH, blk256, 0, stream>>>(buf2, Wo_l, bo + l * H_, tmp, M_, H_, H_, H_);
    resid_ln_kernel<<<M_, blk256, 0, stream>>>(h, tmp, ln1_g + l * H_, ln1_b + l * H_);

    gemm_mfma<1><<<gFF, blk256, 0, stream>>>(h, W1_l, b1 + l * FF_, tmp, M_, FF_, H_, FF_);
    gemm_mfma<0><<<gH, blk256, 0, stream>>>(tmp, W2_l, b2 + l * H_, buf2, M_, H_, FF_, H_);
    resid_ln_kernel<<<M_, blk256, 0, stream>>>(h, buf2, ln2_g + l * H_, ln2_b + l * H_);
  }

  // classifier + online-softmax NLL, chunked over V
  loss_init_kernel<<<(M_ + 255) / 256, blk256, 0, stream>>>(marr, sarr, ylg);
  for (int c0 = 0; c0 < V_; c0 += VC_) {
    int vc = (V_ - c0) < VC_ ? (V_ - c0) : VC_;
    dim3 gC((vc + 127) / 128, M_ / 128);
    gemm_mfma<0><<<gC, blk256, 0, stream>>>(h, Wc + c0, bc + c0, tmp, M_, vc, H_, V_);
    loss_update_kernel<<<M_, blk256, 0, stream>>>(tmp, y, marr, sarr, ylg, c0, vc);
  }
  loss_final_kernel<<<1, blk256, 0, stream>>>(marr, sarr, ylg, (float*)d_out);
}

// Round 3
// 6831.495 us; speedup vs baseline: 4.9251x; 1.3147x over previous
//
#include <hip/hip_runtime.h>
#include <hip/hip_bf16.h>
#include <math.h>

// Problem constants
constexpr int B_  = 64;
constexpr int T_  = 120;
constexpr int TITLE_ = 20;
constexpr int H_  = 768;
constexpr int L_  = 12;
constexpr int NH_ = 12;
constexpr int DH_ = 64;
constexpr int FF_ = 3072;
constexpr int V_  = 21128;
constexpr int M_  = B_ * T_;      // 7680 tokens
constexpr int VC_ = 2048;         // classifier V-chunk width

typedef __attribute__((ext_vector_type(8))) _Float16 f16x8;
typedef __attribute__((ext_vector_type(4))) _Float16 f16x4;
typedef __attribute__((ext_vector_type(4))) float f32x4;

// ---------------- block reductions ------------------------------------------
__device__ __forceinline__ float block_reduce_sum(float v) {
  __shared__ float red[8];
  #pragma unroll
  for (int o = 32; o > 0; o >>= 1) v += __shfl_down(v, o, 64);
  int lane = threadIdx.x & 63, w = threadIdx.x >> 6;
  __syncthreads();
  if (lane == 0) red[w] = v;
  __syncthreads();
  float total = 0.0f;
  int nw = (blockDim.x + 63) >> 6;
  for (int i = 0; i < nw; i++) total += red[i];
  return total;
}

__device__ __forceinline__ float block_reduce_max(float v) {
  __shared__ float red[8];
  #pragma unroll
  for (int o = 32; o > 0; o >>= 1) v = fmaxf(v, __shfl_down(v, o, 64));
  int lane = threadIdx.x & 63, w = threadIdx.x >> 6;
  __syncthreads();
  if (lane == 0) red[w] = v;
  __syncthreads();
  float total = -1e30f;
  int nw = (blockDim.x + 63) >> 6;
  for (int i = 0; i < nw; i++) total = fmaxf(total, red[i]);
  return total;
}

// ---------------- embedding + LN --------------------------------------------
__global__ __launch_bounds__(256) void embed_ln_kernel(
    const int* __restrict__ x, const float* __restrict__ we,
    const float* __restrict__ pe, const float* __restrict__ te,
    const float* __restrict__ g, const float* __restrict__ b,
    float* __restrict__ h) {
  int tok = blockIdx.x;
  int t = tok % T_;
  int wid = x[tok];
  int tid = threadIdx.x;
  float vals[3];
  float lsum = 0.0f;
  #pragma unroll
  for (int i = 0; i < 3; i++) {
    int c = tid + i * 256;
    float v = we[wid * H_ + c] + pe[t * H_ + c] + te[c];
    vals[i] = v; lsum += v;
  }
  float mean = block_reduce_sum(lsum) * (1.0f / H_);
  float lvar = 0.0f;
  #pragma unroll
  for (int i = 0; i < 3; i++) { float d = vals[i] - mean; lvar += d * d; }
  float var = block_reduce_sum(lvar) * (1.0f / H_);
  float rstd = rsqrtf(var + 1e-12f);
  #pragma unroll
  for (int i = 0; i < 3; i++) {
    int c = tid + i * 256;
    h[tok * H_ + c] = (vals[i] - mean) * rstd * g[c] + b[c];
  }
}

// ---------------- residual + LN (in place on h) ------------------------------
__global__ __launch_bounds__(256) void resid_ln_kernel(
    float* __restrict__ h, const float* __restrict__ delta,
    const float* __restrict__ g, const float* __restrict__ b) {
  int tok = blockIdx.x;
  int tid = threadIdx.x;
  float vals[3];
  float lsum = 0.0f;
  #pragma unroll
  for (int i = 0; i < 3; i++) {
    int c = tid + i * 256;
    float v = h[tok * H_ + c] + delta[tok * H_ + c];
    vals[i] = v; lsum += v;
  }
  float mean = block_reduce_sum(lsum) * (1.0f / H_);
  float lvar = 0.0f;
  #pragma unroll
  for (int i = 0; i < 3; i++) { float d = vals[i] - mean; lvar += d * d; }
  float var = block_reduce_sum(lvar) * (1.0f / H_);
  float rstd = rsqrtf(var + 1e-12f);
  #pragma unroll
  for (int i = 0; i < 3; i++) {
    int c = tid + i * 256;
    h[tok * H_ + c] = (vals[i] - mean) * rstd * g[c] + b[c];
  }
}

// ---------------- pack kernels: f32 -> fragment-major f16 hi/lo tiles --------
// Tile = 16 rows x 32 k. Lane l holds row (l&15), k (l>>4)*8+e.
// Layout: tile chunk = 2KB: [hi: 64 lanes x 16B][lo: 64 lanes x 16B].
// pack_a: A[Mr,K] row-major, Mr/16 x K/32 tiles, tile index = tm*Kt+ks.
__global__ __launch_bounds__(256) void pack_a_kernel(
    const float* __restrict__ A, _Float16* __restrict__ Ap, int Mt, int K) {
  int Kt = K >> 5;
  int tile = blockIdx.x * 4 + (threadIdx.x >> 6);
  if (tile >= Mt * Kt) return;
  int tm = tile / Kt, ks = tile % Kt;
  int l = threadIdx.x & 63;
  const float* src = A + (size_t)(tm * 16 + (l & 15)) * K + ks * 32 + (l >> 4) * 8;
  float4 x0 = *reinterpret_cast<const float4*>(src);
  float4 x1 = *reinterpret_cast<const float4*>(src + 4);
  float xs[8] = {x0.x, x0.y, x0.z, x0.w, x1.x, x1.y, x1.z, x1.w};
  f16x8 hi, lo;
  #pragma unroll
  for (int e = 0; e < 8; e++) {
    _Float16 hv = (_Float16)xs[e];
    hi[e] = hv;
    lo[e] = (_Float16)(xs[e] - (float)hv);
  }
  _Float16* dst = Ap + (size_t)tile * 1024;
  *reinterpret_cast<f16x8*>(dst + l * 8) = hi;
  *reinterpret_cast<f16x8*>(dst + 512 + l * 8) = lo;
}

// pack_w: up to 3 segment matrices (fused QKV), column guard + zero pad.
// W[k][n] with n = tn*16+(l&15); source = Wseg[(k)*ldw + n - seg*nseg].
__global__ __launch_bounds__(256) void pack_w_kernel(
    const float* __restrict__ W0, const float* __restrict__ W1,
    const float* __restrict__ W2, int nseg, int Nreal,
    _Float16* __restrict__ Wp, int K, int ldw, int Ntiles) {
  int Kt = K >> 5;
  int tile = blockIdx.x * 4 + (threadIdx.x >> 6);
  if (tile >= Ntiles * Kt) return;
  int tn = tile / Kt, ks = tile % Kt;
  int l = threadIdx.x & 63;
  int n = tn * 16 + (l & 15);
  int k0 = ks * 32 + (l >> 4) * 8;
  const float* Wsel = W0; int nc = n;
  if (n >= 2 * nseg)      { Wsel = W2; nc = n - 2 * nseg; }
  else if (n >= nseg)     { Wsel = W1; nc = n - nseg; }
  f16x8 hi, lo;
  #pragma unroll
  for (int e = 0; e < 8; e++) {
    float v = (n < Nreal) ? Wsel[(size_t)(k0 + e) * ldw + nc] : 0.0f;
    _Float16 hv = (_Float16)v;
    hi[e] = hv;
    lo[e] = (_Float16)(v - (float)hv);
  }
  _Float16* dst = Wp + (size_t)tile * 1024;
  *reinterpret_cast<f16x8*>(dst + l * 8) = hi;
  *reinterpret_cast<f16x8*>(dst + 512 + l * 8) = lo;
}

// ---------------- packed-operand MFMA GEMM -----------------------------------
// C = A @ W + bias from pre-packed f16 hi/lo fragment tiles (3-term split).
// 128x128 tile, BK=32, 4 waves 2x2, global_load_lds staging, dbuf LDS.
// Segmented bias/output (bseg) supports fused QKV (seg stride cstride).
template <int ACT>
__global__ __launch_bounds__(256) void gemm_pack(
    const _Float16* __restrict__ Ap, const _Float16* __restrict__ Wp,
    const float* __restrict__ b0, const float* __restrict__ b1,
    const float* __restrict__ b2, int bseg,
    float* __restrict__ C, size_t cstride, int ldc,
    int M, int N, int K) {
  const int Kt = K >> 5;
  __shared__ _Float16 sm[2][16384];   // 2 x (A 16KB + B 16KB)
  const int tid = threadIdx.x, lane = tid & 63, wv = tid >> 6;
  const int wm = wv >> 1, wn = wv & 1;
  const int lr = lane & 15, lg = lane >> 4;
  const int mt0 = blockIdx.y * 8, nt0 = blockIdx.x * 8;

  const bool isB = (wv >= 2);
  const char* src = (const char*)(isB ? Wp : Ap);
  const int tbase = isB ? nt0 : mt0;
  const int lofs = isB ? 8192 : 0;

  auto stage = [&](int ks, int buf) {
    #pragma unroll
    for (int q = 0; q < 8; q++) {
      int c = ((wv & 1) << 3) + q;
      int tile = c >> 1, hl = c & 1;
      const char* gp = src + (((size_t)(tbase + tile) * Kt + ks) << 11)
                           + (hl << 10) + lane * 16;
      _Float16* lp = &sm[buf][lofs + (tile * 2 + hl) * 512];
      __builtin_amdgcn_global_load_lds(
          (const __attribute__((address_space(1))) unsigned int*)gp,
          (__attribute__((address_space(3))) unsigned int*)lp, 16, 0, 0);
    }
  };

  f32x4 acc[4][4] = {};
  stage(0, 0);
  __syncthreads();
  int cur = 0;
  for (int t = 0; t < Kt; t++) {
    if (t + 1 < Kt) stage(t + 1, cur ^ 1);   // loads fly under this tile's MFMA
    const _Float16* base = &sm[cur][0];
    f16x8 ah[4], al[4], bh[4], bl[4];
    #pragma unroll
    for (int i = 0; i < 4; i++) {
      int ta = (wm * 4 + i) * 2;
      ah[i] = *reinterpret_cast<const f16x8*>(&base[ta * 512 + lane * 8]);
      al[i] = *reinterpret_cast<const f16x8*>(&base[(ta + 1) * 512 + lane * 8]);
      int tb = (wn * 4 + i) * 2;
      bh[i] = *reinterpret_cast<const f16x8*>(&base[8192 + tb * 512 + lane * 8]);
      bl[i] = *reinterpret_cast<const f16x8*>(&base[8192 + (tb + 1) * 512 + lane * 8]);
    }
    #pragma unroll
    for (int i = 0; i < 4; i++)
      #pragma unroll
      for (int j = 0; j < 4; j++) {
        acc[i][j] = __builtin_amdgcn_mfma_f32_16x16x32_f16(ah[i], bh[j], acc[i][j], 0, 0, 0);
        acc[i][j] = __builtin_amdgcn_mfma_f32_16x16x32_f16(ah[i], bl[j], acc[i][j], 0, 0, 0);
        acc[i][j] = __builtin_amdgcn_mfma_f32_16x16x32_f16(al[i], bh[j], acc[i][j], 0, 0, 0);
      }
    __syncthreads();   // drains next-tile loads + all LDS reads, then swap
    cur ^= 1;
  }

  // epilogue: C/D layout col=lane&15, row=(lane>>4)*4+reg
  #pragma unroll
  for (int j = 0; j < 4; j++) {
    int ncol = blockIdx.x * 128 + wn * 64 + j * 16 + lr;
    if (ncol < N) {
      int seg = 0, nc = ncol;
      if (ncol >= 2 * bseg)      { seg = 2; nc = ncol - 2 * bseg; }
      else if (ncol >= bseg)     { seg = 1; nc = ncol - bseg; }
      const float* bp = (seg == 0) ? b0 : ((seg == 1) ? b1 : b2);
      float bias = bp[nc];
      float* Cp = C + (size_t)seg * cstride;
      #pragma unroll
      for (int i = 0; i < 4; i++) {
        #pragma unroll
        for (int r = 0; r < 4; r++) {
          int m = blockIdx.y * 128 + wm * 64 + i * 16 + lg * 4 + r;
          float v = acc[i][j][r] + bias;
          if (ACT == 1) v = 0.5f * v * (1.0f + erff(v * 0.70710678118654752f));
          Cp[(size_t)m * ldc + nc] = v;
        }
      }
    }
  }
}

// ---------------- MFMA attention: one block per (b, head) --------------------
__global__ __launch_bounds__(512) void attn_mfma_kernel(
    const float* __restrict__ qb, const float* __restrict__ kb,
    const float* __restrict__ vb, float* __restrict__ ctx) {
  constexpr int KP = 72;
  constexpr int VP = 136;
  constexpr int PP = 136;
  __shared__ alignas(16) _Float16 Kh[128 * KP];
  __shared__ alignas(16) _Float16 Kl[128 * KP];
  __shared__ alignas(16) _Float16 Vth[64 * VP];
  __shared__ alignas(16) _Float16 Vtl[64 * VP];
  __shared__ alignas(16) _Float16 Ph[128 * PP];
  __shared__ alignas(16) _Float16 Pl[128 * PP];

  const int hh = blockIdx.x % NH_;
  const int b  = blockIdx.x / NH_;
  const int bt0 = b * T_;
  const int tid = threadIdx.x;
  const int lane = tid & 63;
  const int wv = tid >> 6;
  const int lr = lane & 15, lg = lane >> 4;
  const int r0 = wv * 16;

  {
    const int sc0 = (tid & 15) * 4;
    #pragma unroll
    for (int pass = 0; pass < 4; pass++) {
      int t = pass * 32 + (tid >> 4);
      float4 kv = make_float4(0.f, 0.f, 0.f, 0.f);
      float4 vv = make_float4(0.f, 0.f, 0.f, 0.f);
      if (t < T_) {
        kv = *reinterpret_cast<const float4*>(&kb[(size_t)(bt0 + t) * H_ + hh * DH_ + sc0]);
        vv = *reinterpret_cast<const float4*>(&vb[(size_t)(bt0 + t) * H_ + hh * DH_ + sc0]);
      }
      float ka[4] = {kv.x, kv.y, kv.z, kv.w};
      f16x4 khv, klv;
      #pragma unroll
      for (int i = 0; i < 4; i++) {
        _Float16 hv = (_Float16)ka[i];
        khv[i] = hv;
        klv[i] = (_Float16)(ka[i] - (float)hv);
      }
      *reinterpret_cast<f16x4*>(&Kh[t * KP + sc0]) = khv;
      *reinterpret_cast<f16x4*>(&Kl[t * KP + sc0]) = klv;
      float va[4] = {vv.x, vv.y, vv.z, vv.w};
      #pragma unroll
      for (int i = 0; i < 4; i++) {
        _Float16 hv = (_Float16)va[i];
        Vth[(sc0 + i) * VP + t] = hv;
        Vtl[(sc0 + i) * VP + t] = (_Float16)(va[i] - (float)hv);
      }
    }
  }
  __syncthreads();

  f16x8 aqh[2], aql[2];
  #pragma unroll
  for (int ks = 0; ks < 2; ks++) {
    const float* qp = qb + (size_t)(bt0 + r0 + lr) * H_ + hh * DH_ + ks * 32 + lg * 8;
    float4 x0 = *reinterpret_cast<const float4*>(qp);
    float4 x1 = *reinterpret_cast<const float4*>(qp + 4);
    float xs[8] = {x0.x, x0.y, x0.z, x0.w, x1.x, x1.y, x1.z, x1.w};
    #pragma unroll
    for (int e = 0; e < 8; e++) {
      _Float16 hv = (_Float16)xs[e];
      aqh[ks][e] = hv;
      aql[ks][e] = (_Float16)(xs[e] - (float)hv);
    }
  }

  f32x4 accS[8] = {};
  #pragma unroll
  for (int j = 0; j < 8; j++) {
    #pragma unroll
    for (int ks = 0; ks < 2; ks++) {
      f16x8 kh = *reinterpret_cast<const f16x8*>(&Kh[(j * 16 + lr) * KP + ks * 32 + lg * 8]);
      f16x8 kl = *reinterpret_cast<const f16x8*>(&Kl[(j * 16 + lr) * KP + ks * 32 + lg * 8]);
      accS[j] = __builtin_amdgcn_mfma_f32_16x16x32_f16(aqh[ks], kh, accS[j], 0, 0, 0);
      accS[j] = __builtin_amdgcn_mfma_f32_16x16x32_f16(aqh[ks], kl, accS[j], 0, 0, 0);
      accS[j] = __builtin_amdgcn_mfma_f32_16x16x32_f16(aql[ks], kh, accS[j], 0, 0, 0);
    }
  }

  float invs[4];
  #pragma unroll
  for (int rr = 0; rr < 4; rr++) {
    int row = r0 + lg * 4 + rr;
    float m = -1e30f;
    float sv[8];
    #pragma unroll
    for (int j = 0; j < 8; j++) {
      int col = j * 16 + lr;
      float s = accS[j][rr] * 0.125f;
      bool allowed = (col < TITLE_) || (row >= TITLE_ && col <= row && col < T_);
      s = allowed ? s : -1e30f;
      sv[j] = s;
      m = fmaxf(m, s);
    }
    #pragma unroll
    for (int o = 8; o >= 1; o >>= 1) m = fmaxf(m, __shfl_xor(m, o, 64));
    float sum = 0.0f;
    #pragma unroll
    for (int j = 0; j < 8; j++) {
      float p = expf(sv[j] - m);
      sum += p;
      int col = j * 16 + lr;
      _Float16 ph = (_Float16)p;
      Ph[row * PP + col] = ph;
      Pl[row * PP + col] = (_Float16)(p - (float)ph);
    }
    #pragma unroll
    for (int o = 8; o >= 1; o >>= 1) sum += __shfl_xor(sum, o, 64);
    invs[rr] = 1.0f / sum;
  }
  __syncthreads();

  f32x4 accB[4] = {};
  #pragma unroll
  for (int ks = 0; ks < 4; ks++) {
    int t0 = ks * 32 + lg * 8;
    f16x8 pah = *reinterpret_cast<const f16x8*>(&Ph[(r0 + lr) * PP + t0]);
    f16x8 pal = *reinterpret_cast<const f16x8*>(&Pl[(r0 + lr) * PP + t0]);
    #pragma unroll
    for (int tn = 0; tn < 4; tn++) {
      f16x8 vh = *reinterpret_cast<const f16x8*>(&Vth[(tn * 16 + lr) * VP + t0]);
      f16x8 vl = *reinterpret_cast<const f16x8*>(&Vtl[(tn * 16 + lr) * VP + t0]);
      accB[tn] = __builtin_amdgcn_mfma_f32_16x16x32_f16(pah, vh, accB[tn], 0, 0, 0);
      accB[tn] = __builtin_amdgcn_mfma_f32_16x16x32_f16(pah, vl, accB[tn], 0, 0, 0);
      accB[tn] = __builtin_amdgcn_mfma_f32_16x16x32_f16(pal, vh, accB[tn], 0, 0, 0);
    }
  }

  #pragma unroll
  for (int tn = 0; tn < 4; tn++) {
    int n = tn * 16 + lr;
    #pragma unroll
    for (int rr = 0; rr < 4; rr++) {
      int row = r0 + lg * 4 + rr;
      if (row < T_)
        ctx[(size_t)(bt0 + row) * H_ + hh * DH_ + n] = accB[tn][rr] * invs[rr];
    }
  }
}

// ---------------- online-softmax loss over V chunks ---------------------------
__global__ void loss_init_kernel(float* marr, float* sarr, float* ylg) {
  int i = blockIdx.x * 256 + threadIdx.x;
  if (i < M_) { marr[i] = -1e30f; sarr[i] = 0.0f; ylg[i] = 0.0f; }
}

__global__ __launch_bounds__(256) void loss_update_kernel(
    const float* __restrict__ logits, const int* __restrict__ y,
    float* __restrict__ marr, float* __restrict__ sarr, float* __restrict__ ylg,
    int c0, int vc) {
  int tok = blockIdx.x;
  int tid = threadIdx.x;
  const float* row = logits + (size_t)tok * vc;
  float lmax = -1e30f;
  for (int i = tid; i < vc; i += 256) lmax = fmaxf(lmax, row[i]);
  float cmax = block_reduce_max(lmax);
  float mold = marr[tok];
  float sold = sarr[tok];
  float mnew = fmaxf(mold, cmax);
  float lsum = 0.0f;
  for (int i = tid; i < vc; i += 256) lsum += expf(row[i] - mnew);
  float csum = block_reduce_sum(lsum);
  if (tid == 0) {
    marr[tok] = mnew;
    sarr[tok] = sold * expf(mold - mnew) + csum;
    int yt = y[tok];
    if (yt >= c0 && yt < c0 + vc) ylg[tok] = row[yt - c0];
  }
}

__global__ __launch_bounds__(256) void loss_final_kernel(
    const float* __restrict__ marr, const float* __restrict__ sarr,
    const float* __restrict__ ylg, float* __restrict__ out) {
  int tid = threadIdx.x;
  float lsum = 0.0f;
  for (int i = tid; i < M_; i += 256)
    lsum += (marr[i] + logf(sarr[i])) - ylg[i];
  float total = block_reduce_sum(lsum);
  if (tid == 0) out[0] = total / (float)M_;
}

// ---------------- host orchestration -----------------------------------------
extern "C" void kernel_launch(void* const* d_in, const int* in_sizes, int n_in,
                              void* d_out, int out_size, void* d_ws, size_t ws_size,
                              hipStream_t stream) {
  const int*   x        = (const int*)d_in[0];
  const int*   y        = (const int*)d_in[1];
  const float* word_emb = (const float*)d_in[2];
  const float* pos_emb  = (const float*)d_in[3];
  const float* type_emb = (const float*)d_in[4];
  const float* emb_ln_g = (const float*)d_in[5];
  const float* emb_ln_b = (const float*)d_in[6];
  const float* Wq = (const float*)d_in[7];
  const float* Wk = (const float*)d_in[8];
  const float* Wv = (const float*)d_in[9];
  const float* Wo = (const float*)d_in[10];
  const float* W1 = (const float*)d_in[11];
  const float* W2 = (const float*)d_in[12];
  const float* bq = (const float*)d_in[13];
  const float* bk = (const float*)d_in[14];
  const float* bv = (const float*)d_in[15];
  const float* bo = (const float*)d_in[16];
  const float* b1 = (const float*)d_in[17];
  const float* b2 = (const float*)d_in[18];
  const float* ln1_g = (const float*)d_in[19];
  const float* ln1_b = (const float*)d_in[20];
  const float* ln2_g = (const float*)d_in[21];
  const float* ln2_b = (const float*)d_in[22];
  const float* Wc = (const float*)d_in[23];
  const float* bc = (const float*)d_in[24];

  // workspace (floats):
  //   h     [M*H]             @ 0
  //   tmp   [M*FF]            @ 5,898,240   (q,k,v,ctx | FF act | logits)
  //   Apack [M*FF pack 94MB]  @ 29,491,200  (as halves)
  //   Wpack [9.44MB]          @ 53,084,160
  //   marr/sarr/ylg           @ 55,443,456
  float* ws   = (float*)d_ws;
  float* h    = ws;
  float* tmp  = ws + 5898240;
  _Float16* Apack = (_Float16*)(ws + 29491200);
  _Float16* Wpack = (_Float16*)(ws + 53084160);
  float* marr = ws + 55443456;
  float* sarr = marr + M_;
  float* ylg  = sarr + M_;

  float* q   = tmp;
  float* k   = tmp + (size_t)M_ * H_;
  float* v   = tmp + (size_t)2 * M_ * H_;
  float* ctx = tmp + (size_t)3 * M_ * H_;

  dim3 blk256(256);
  const int MT = M_ / 16;              // 480 m-tiles
  const size_t MH = (size_t)M_ * H_;

  embed_ln_kernel<<<M_, blk256, 0, stream>>>(x, word_emb, pos_emb, type_emb,
                                             emb_ln_g, emb_ln_b, h);

  for (int l = 0; l < L_; l++) {
    const float* Wq_l = Wq + (size_t)l * H_ * H_;
    const float* Wk_l = Wk + (size_t)l * H_ * H_;
    const float* Wv_l = Wv + (size_t)l * H_ * H_;
    const float* Wo_l = Wo + (size_t)l * H_ * H_;
    const float* W1_l = W1 + (size_t)l * H_ * FF_;
    const float* W2_l = W2 + (size_t)l * FF_ * H_;

    // fused QKV: one N=2304 GEMM from packed h
    pack_a_kernel<<<(MT * 24 + 3) / 4, blk256, 0, stream>>>(h, Apack, MT, H_);
    pack_w_kernel<<<(144 * 24 + 3) / 4, blk256, 0, stream>>>(
        Wq_l, Wk_l, Wv_l, 768, 2304, Wpack, H_, H_, 144);
    gemm_pack<0><<<dim3(18, 60), blk256, 0, stream>>>(
        Apack, Wpack, bq + l * H_, bk + l * H_, bv + l * H_, 768,
        tmp, MH, H_, M_, 2304, H_);

    attn_mfma_kernel<<<B_ * NH_, 512, 0, stream>>>(q, k, v, ctx);

    pack_a_kernel<<<(MT * 24 + 3) / 4, blk256, 0, stream>>>(ctx, Apack, MT, H_);
    pack_w_kernel<<<(48 * 24 + 3) / 4, blk256, 0, stream>>>(
        Wo_l, Wo_l, Wo_l, H_, H_, Wpack, H_, H_, 48);
    gemm_pack<0><<<dim3(6, 60), blk256, 0, stream>>>(
        Apack, Wpack, bo + l * H_, bo + l * H_, bo + l * H_, H_,
        tmp, 0, H_, M_, H_, H_);
    resid_ln_kernel<<<M_, blk256, 0, stream>>>(h, tmp, ln1_g + l * H_, ln1_b + l * H_);

    pack_a_kernel<<<(MT * 24 + 3) / 4, blk256, 0, stream>>>(h, Apack, MT, H_);
    pack_w_kernel<<<(192 * 24 + 3) / 4, blk256, 0, stream>>>(
        W1_l, W1_l, W1_l, FF_, FF_, Wpack, H_, FF_, 192);
    gemm_pack<1><<<dim3(24, 60), blk256, 0, stream>>>(
        Apack, Wpack, b1 + l * FF_, b1 + l * FF_, b1 + l * FF_, FF_,
        tmp, 0, FF_, M_, FF_, H_);

    pack_a_kernel<<<(MT * 96 + 3) / 4, blk256, 0, stream>>>(tmp, Apack, MT, FF_);
    pack_w_kernel<<<(48 * 96 + 3) / 4, blk256, 0, stream>>>(
        W2_l, W2_l, W2_l, H_, H_, Wpack, FF_, H_, 48);
    gemm_pack<0><<<dim3(6, 60), blk256, 0, stream>>>(
        Apack, Wpack, b2 + l * H_, b2 + l * H_, b2 + l * H_, H_,
        tmp, 0, H_, M_, H_, FF_);
    resid_ln_kernel<<<M_, blk256, 0, stream>>>(h, tmp, ln2_g + l * H_, ln2_b + l * H_);
  }

  // classifier + online-softmax NLL, chunked over V
  pack_a_kernel<<<(MT * 24 + 3) / 4, blk256, 0, stream>>>(h, Apack, MT, H_);
  loss_init_kernel<<<(M_ + 255) / 256, blk256, 0, stream>>>(marr, sarr, ylg);
  for (int c0 = 0; c0 < V_; c0 += VC_) {
    int vc = (V_ - c0) < VC_ ? (V_ - c0) : VC_;
    int nb = (vc + 127) / 128;          // 128-col blocks
    int nt = nb * 8;                    // padded n-tiles
    pack_w_kernel<<<(nt * 24 + 3) / 4, blk256, 0, stream>>>(
        Wc + c0, Wc + c0, Wc + c0, vc, vc, Wpack, H_, V_, nt);
    gemm_pack<0><<<dim3(nb, 60), blk256, 0, stream>>>(
        Apack, Wpack, bc + c0, bc + c0, bc + c0, vc,
        tmp, 0, vc, M_, vc, H_);
    loss_update_kernel<<<M_, blk256, 0, stream>>>(tmp, y, marr, sarr, ylg, c0, vc);
  }
  loss_final_kernel<<<1, blk256, 0, stream>>>(marr, sarr, ylg, (float*)d_out);
}